// Round 1
// baseline (2317.349 us; speedup 1.0000x reference)
//
#include <hip/hip_runtime.h>
#include <math.h>

// ---------------------------------------------------------------------------
// MLVAE pipeline, f32 baseline.
// Dims: N=64, L=2048, C1=64, C2=128, C3=256, LAT=512, LD=64.
// ---------------------------------------------------------------------------

// Generic 'same' conv1d (k=3) + leaky-relu(slope) kernel.
// Grid: (n, COUT/16). Block: 256 = 4 waves; each wave owns 4 consecutive
// output channels, lanes = 64 l-positions, looping l in tiles of 64.
// Weights are wave-uniform -> scalar loads (SMEM pipe), inputs via L1.
template<int CIN, int COUT, int LLEN>
__global__ __launch_bounds__(256) void convk(
    const float* __restrict__ in, const float* __restrict__ W,
    const float* __restrict__ bias, float* __restrict__ out, float slope)
{
  const int n   = blockIdx.x;
  const int wv  = __builtin_amdgcn_readfirstlane(threadIdx.x >> 6);
  const int c0  = blockIdx.y * 16 + wv * 4;
  const int lane = threadIdx.x & 63;
  const float* inn = in + (size_t)n * CIN * LLEN;

  float bs[4];
  #pragma unroll
  for (int q = 0; q < 4; ++q) bs[q] = bias[c0 + q];

  for (int l0 = 0; l0 < LLEN; l0 += 64) {
    const int l  = l0 + lane;
    const int lm = l > 0 ? l - 1 : 0;
    const int lp = l < LLEN - 1 ? l + 1 : LLEN - 1;
    float acc[4] = {bs[0], bs[1], bs[2], bs[3]};
    for (int ci = 0; ci < CIN; ++ci) {
      const float* row = inn + ci * LLEN;
      float x0 = row[l];
      float xm = row[lm]; if (l == 0)        xm = 0.f;
      float xp = row[lp]; if (l == LLEN - 1) xp = 0.f;
      #pragma unroll
      for (int q = 0; q < 4; ++q) {
        const float* w = W + ((size_t)(c0 + q) * CIN + ci) * 3;
        acc[q] = fmaf(xm, w[0], fmaf(x0, w[1], fmaf(xp, w[2], acc[q])));
      }
    }
    #pragma unroll
    for (int q = 0; q < 4; ++q) {
      float v = acc[q];
      v = v > 0.f ? v : slope * v;
      out[((size_t)n * COUT + c0 + q) * LLEN + l] = v;
    }
  }
}

// conv3 (CIN=128 -> COUT=256, lrelu) fused with the three Linear(L->2) heads.
// h3 is never materialized: each activation immediately feeds 6 dot products
// (cm/sm/sl x d in {0,1}); per-lane partials reduced by wave shuffle at end.
__global__ __launch_bounds__(256) void conv3_heads_kernel(
    const float* __restrict__ h2,   // [64][128][2048]
    const float* __restrict__ W3,   // [256][128][3]
    const float* __restrict__ b3,
    const float* __restrict__ cmW, const float* __restrict__ cmB,
    const float* __restrict__ smW, const float* __restrict__ smB,
    const float* __restrict__ slW, const float* __restrict__ slB,
    float* __restrict__ cm, float* __restrict__ sm, float* __restrict__ sl)
{
  const int n    = blockIdx.x;
  const int wv   = __builtin_amdgcn_readfirstlane(threadIdx.x >> 6);
  const int c0   = blockIdx.y * 16 + wv * 4;
  const int lane = threadIdx.x & 63;
  const float* h2n = h2 + (size_t)n * 128 * 2048;

  float bs[4];
  #pragma unroll
  for (int q = 0; q < 4; ++q) bs[q] = b3[c0 + q];

  float hacc[4][6];
  #pragma unroll
  for (int q = 0; q < 4; ++q)
    #pragma unroll
    for (int h = 0; h < 6; ++h) hacc[q][h] = 0.f;

  for (int l0 = 0; l0 < 2048; l0 += 64) {
    const int l  = l0 + lane;
    const int lm = l > 0 ? l - 1 : 0;
    const int lp = l < 2047 ? l + 1 : 2047;
    // head weights for this l (hoisted out of q loop)
    const float hw0 = cmW[l],        hw1 = cmW[2048 + l];
    const float hw2 = smW[l],        hw3 = smW[2048 + l];
    const float hw4 = slW[l],        hw5 = slW[2048 + l];

    float acc[4] = {bs[0], bs[1], bs[2], bs[3]};
    for (int ci = 0; ci < 128; ++ci) {
      const float* row = h2n + ci * 2048;
      float x0 = row[l];
      float xm = row[lm]; if (l == 0)    xm = 0.f;
      float xp = row[lp]; if (l == 2047) xp = 0.f;
      #pragma unroll
      for (int q = 0; q < 4; ++q) {
        const float* w = W3 + ((size_t)(c0 + q) * 128 + ci) * 3;
        acc[q] = fmaf(xm, w[0], fmaf(x0, w[1], fmaf(xp, w[2], acc[q])));
      }
    }
    #pragma unroll
    for (int q = 0; q < 4; ++q) {
      float v = acc[q];
      v = v > 0.f ? v : 0.01f * v;   // lrelu
      hacc[q][0] = fmaf(v, hw0, hacc[q][0]);
      hacc[q][1] = fmaf(v, hw1, hacc[q][1]);
      hacc[q][2] = fmaf(v, hw2, hacc[q][2]);
      hacc[q][3] = fmaf(v, hw3, hacc[q][3]);
      hacc[q][4] = fmaf(v, hw4, hacc[q][4]);
      hacc[q][5] = fmaf(v, hw5, hacc[q][5]);
    }
  }

  // wave (64-lane) reduction of the 24 partials
  #pragma unroll
  for (int q = 0; q < 4; ++q)
    #pragma unroll
    for (int h = 0; h < 6; ++h) {
      float v = hacc[q][h];
      for (int off = 32; off > 0; off >>= 1) v += __shfl_down(v, off, 64);
      hacc[q][h] = v;
    }

  if (lane == 0) {
    #pragma unroll
    for (int q = 0; q < 4; ++q) {
      const int c = c0 + q;
      cm[(size_t)n * 512 + c * 2 + 0] = hacc[q][0] + cmB[0];
      cm[(size_t)n * 512 + c * 2 + 1] = hacc[q][1] + cmB[1];
      sm[(size_t)n * 512 + c * 2 + 0] = hacc[q][2] + smB[0];
      sm[(size_t)n * 512 + c * 2 + 1] = hacc[q][3] + smB[1];
      sl[(size_t)n * 512 + c * 2 + 0] = hacc[q][4] + slB[0];
      sl[(size_t)n * 512 + c * 2 + 1] = hacc[q][5] + slB[1];
    }
  }
}

// group-evidence fusion + reparameterization (z_c [512], z_s [64][512])
__global__ __launch_bounds__(256) void group_reparam_kernel(
    const float* __restrict__ cm, const float* __restrict__ sm,
    const float* __restrict__ sl, const float* __restrict__ eps_c,
    const float* __restrict__ eps_s, float* __restrict__ zc,
    float* __restrict__ zs)
{
  const int j = blockIdx.x * 256 + threadIdx.x;
  if (j >= 512) return;
  float sp = 0.f, smp = 0.f;
  for (int n = 0; n < 64; ++n) {
    float mu = cm[n * 512 + j];
    float p  = expf(-mu);          // class_logvar == class_mu (bug-faithful)
    sp  += p;
    smp = fmaf(mu, p, smp);
  }
  float gv  = 1.f / sp;
  float gmu = gv * smp;
  zc[j] = eps_c[j] * sqrtf(gv) + gmu;   // exp(0.5*log gv) = sqrt(gv)
  for (int n = 0; n < 64; ++n)
    zs[n * 512 + j] = eps_s[n * 512 + j] * expf(0.5f * sl[n * 512 + j]) + sm[n * 512 + j];
}

// content = pc_W[16384,512] @ z_c + pc_b ; one wave per row, 4 rows/block
__global__ __launch_bounds__(256) void matvec_content_kernel(
    const float* __restrict__ pcW, const float* __restrict__ pcb,
    const float* __restrict__ zc, float* __restrict__ content)
{
  const int r    = blockIdx.x * 4 + (threadIdx.x >> 6);
  const int lane = threadIdx.x & 63;
  const float* row = pcW + (size_t)r * 512;
  float s = 0.f;
  #pragma unroll
  for (int i = 0; i < 8; ++i) {
    int k = lane + i * 64;
    s = fmaf(row[k], zc[k], s);
  }
  for (int off = 32; off > 0; off >>= 1) s += __shfl_down(s, off, 64);
  if (lane == 0) content[r] = s + pcb[r];
}

// m0[n,r] = sum_k z_s[n,k]*ps_W[r,k] + ps_b[r]; block = 4 rows x 64 n-lanes,
// ps_W rows staged in LDS (coalesced), z_s read through cache.
__global__ __launch_bounds__(256) void gemm_m0_kernel(
    const float* __restrict__ psW, const float* __restrict__ psb,
    const float* __restrict__ zs, float* __restrict__ m0)
{
  __shared__ float wrow[4][512];
  const int r0 = blockIdx.x * 4;
  for (int idx = threadIdx.x; idx < 2048; idx += 256)
    ((float*)wrow)[idx] = psW[(size_t)r0 * 512 + idx];
  __syncthreads();
  const int rq = threadIdx.x >> 6;
  const int nn = threadIdx.x & 63;
  const float* zr = zs + nn * 512;
  float s = 0.f;
  #pragma unroll 4
  for (int k = 0; k < 512; k += 4) {
    float4 z4 = *(const float4*)(zr + k);
    float4 w4 = *(const float4*)(&wrow[rq][k]);
    s = fmaf(z4.x, w4.x, fmaf(z4.y, w4.y, fmaf(z4.z, w4.z, fmaf(z4.w, w4.w, s))));
  }
  m0[(size_t)nn * 16384 + r0 + rq] = s + psb[r0 + rq];
}

// out[n,k] = sum_j m2[n,j] * src[k-j]  (full convolution, 4096 (x) 4096 -> 8191)
// Per-thread: 8 consecutive k via sliding register window (1 src + 1 m LDS
// read per 8 FMAs in the unrolled steady state).
__global__ __launch_bounds__(256) void final_conv_kernel(
    const float* __restrict__ m2, const float* __restrict__ src,
    float* __restrict__ out)
{
  __shared__ float s_src[4096];
  __shared__ float s_m[4096];
  const int n = blockIdx.x;
  for (int i = threadIdx.x; i < 4096; i += 256) {
    s_src[i] = src[i];
    s_m[i]   = m2[(size_t)n * 4096 + i];
  }
  __syncthreads();

  const int k0 = blockIdx.y * 2048 + threadIdx.x * 8;
  int jlo = k0 - 4095; if (jlo < 0) jlo = 0;
  int jhi = k0 + 7;    if (jhi > 4095) jhi = 4095;

  float acc[8];
  #pragma unroll
  for (int ii = 0; ii < 8; ++ii) acc[ii] = 0.f;

  // window invariant at loop head (j = J): Wr[p] = padded_src(k0 + p - J)
  float Wr[8];
  #pragma unroll
  for (int p = 0; p < 8; ++p) {
    int d  = k0 + p - jlo;
    int dc = d & 4095;
    float v = s_src[dc];
    Wr[p] = (d == dc) ? v : 0.f;
  }

  int j = jlo;
  for (; j + 7 <= jhi; j += 8) {
    #pragma unroll
    for (int s = 0; s < 8; ++s) {
      float mj = s_m[j + s];
      #pragma unroll
      for (int ii = 0; ii < 8; ++ii)
        acc[ii] = fmaf(mj, Wr[(ii - s) & 7], acc[ii]);
      int d  = k0 - (j + s) - 1;          // next value entering the window
      int dc = d < 0 ? 0 : d;             // d <= 4094 guaranteed
      float nv = s_src[dc];
      if (d < 0) nv = 0.f;
      Wr[(7 - s) & 7] = nv;
    }
  }
  for (; j <= jhi; ++j) {                  // remainder (<8 steps)
    float mj = s_m[j];
    #pragma unroll
    for (int ii = 0; ii < 8; ++ii) {
      int d  = k0 + ii - j;
      int dc = d & 4095;
      float sv = s_src[dc];
      if (d != dc) sv = 0.f;
      acc[ii] = fmaf(mj, sv, acc[ii]);
    }
  }

  #pragma unroll
  for (int ii = 0; ii < 8; ++ii) {
    int k = k0 + ii;
    if (k < 8191) out[(size_t)n * 8191 + k] = acc[ii];
  }
}

extern "C" void kernel_launch(void* const* d_in, const int* in_sizes, int n_in,
                              void* d_out, int out_size, void* d_ws, size_t ws_size,
                              hipStream_t stream) {
  const float* x    = (const float*)d_in[0];
  const float* W1   = (const float*)d_in[1];
  const float* b1   = (const float*)d_in[2];
  const float* W2   = (const float*)d_in[3];
  const float* b2   = (const float*)d_in[4];
  const float* W3   = (const float*)d_in[5];
  const float* b3   = (const float*)d_in[6];
  const float* cmW  = (const float*)d_in[7];
  const float* cmB  = (const float*)d_in[8];
  const float* smW  = (const float*)d_in[9];
  const float* smB  = (const float*)d_in[10];
  const float* slW  = (const float*)d_in[11];
  const float* slB  = (const float*)d_in[12];
  const float* pcW  = (const float*)d_in[13];
  const float* pcb  = (const float*)d_in[14];
  const float* psW  = (const float*)d_in[15];
  const float* psb  = (const float*)d_in[16];
  const float* V1   = (const float*)d_in[17];
  const float* c1   = (const float*)d_in[18];
  const float* V2   = (const float*)d_in[19];
  const float* c2   = (const float*)d_in[20];
  const float* epsc = (const float*)d_in[21];
  const float* epss = (const float*)d_in[22];
  float* out = (float*)d_out;

  // Workspace layout (floats). Peak live = h1(32MB) + h2(64MB) = 96 MB;
  // all small buffers overlay h1 (only needed after conv2 has consumed h1).
  float* ws = (float*)d_ws;
  float* h1 = ws;                    // [64][64][2048]   = 8388608 f
  float* h2 = h1 + 8388608;          // [64][128][2048]  = 16777216 f
  float* sm0     = h1;               // overlay region (h1 dead after conv2)
  float* cm      = sm0;              // [64][512]
  float* smh     = cm + 32768;       // [64][512]
  float* slh     = smh + 32768;      // [64][512]
  float* zc      = slh + 32768;      // [512]
  float* zs      = zc + 512;         // [64][512]
  float* content = zs + 32768;       // [16384]
  float* d1s     = content + 16384;  // [128][64]
  float* srcb    = d1s + 8192;       // [4096]
  float* m0      = srcb + 4096;      // [64][16384] = 1048576 f
  float* m1      = m0 + 1048576;     // [64][128][64] = 524288 f
  float* m2      = m1 + 524288;      // [64][64][64]  = 262144 f
  (void)ws_size; (void)in_sizes; (void)n_in; (void)out_size;

  // ---- encoder ----
  convk<1,   64, 2048><<<dim3(64, 4), 256, 0, stream>>>(x,  W1, b1, h1, 0.01f);
  convk<64, 128, 2048><<<dim3(64, 8), 256, 0, stream>>>(h1, W2, b2, h2, 0.01f);
  conv3_heads_kernel<<<dim3(64, 16), 256, 0, stream>>>(h2, W3, b3, cmW, cmB,
                                                       smW, smB, slW, slB,
                                                       cm, smh, slh);
  // ---- group evidence + reparameterize ----
  group_reparam_kernel<<<2, 256, 0, stream>>>(cm, smh, slh, epsc, epss, zc, zs);

  // ---- content path: projection + 2 convs -> source ----
  matvec_content_kernel<<<4096, 256, 0, stream>>>(pcW, pcb, zc, content);
  convk<256, 128, 64><<<dim3(1, 8), 256, 0, stream>>>(content, V1, c1, d1s, 0.f);
  convk<128,  64, 64><<<dim3(1, 4), 256, 0, stream>>>(d1s,     V2, c2, srcb, 0.f);

  // ---- style path: GEMM + 2 convs ----
  gemm_m0_kernel<<<4096, 256, 0, stream>>>(psW, psb, zs, m0);
  convk<256, 128, 64><<<dim3(64, 8), 256, 0, stream>>>(m0, V1, c1, m1, 0.f);
  convk<128,  64, 64><<<dim3(64, 4), 256, 0, stream>>>(m1, V2, c2, m2, 0.f);

  // ---- final full 1-D convolution ----
  final_conv_kernel<<<dim3(64, 4), 256, 0, stream>>>(m2, srcb, out);
}

// Round 2
// 1108.215 us; speedup vs baseline: 2.0911x; 2.0911x over previous
//
#include <hip/hip_runtime.h>
#include <math.h>

// ---------------------------------------------------------------------------
// MLVAE pipeline, optimized f32.
// Dims: N=64, L=2048, C1=64, C2=128, C3=256, LAT=512, LD=64.
// ---------------------------------------------------------------------------

__device__ __forceinline__ float lrelu_s(float v, float slope) {
  return v > 0.f ? v : slope * v;
}

// Large-L conv1d k=3 'same' + leaky-relu. Lane-vectorized: each lane owns 4
// consecutive l (float4 load), each wave 8 output channels. Taps from register
// neighbors; 2 edge scalar loads. Weights wave-uniform -> SGPR.
// Grid: (n, COUT/32, LLEN/256). Block 256 = 4 waves.
template<int CIN, int COUT, int LLEN>
__global__ __launch_bounds__(256) void convlv(
    const float* __restrict__ in, const float* __restrict__ W,
    const float* __restrict__ bias, float* __restrict__ out, float slope)
{
  const int n    = blockIdx.x;
  const int wv   = __builtin_amdgcn_readfirstlane(threadIdx.x >> 6);
  const int c0   = blockIdx.y * 32 + wv * 8;
  const int lane = threadIdx.x & 63;
  const int lbase = blockIdx.z * 256 + lane * 4;
  const float* inn = in + (size_t)n * CIN * LLEN;

  const bool bm = (lbase == 0);
  const bool bp = (lbase + 4 == LLEN);
  unsigned o0 = (unsigned)lbase;
  unsigned om = (unsigned)lbase - 1u + (bm ? 1u : 0u);
  unsigned op = (unsigned)lbase + 4u - (bp ? 1u : 0u);

  float acc[8][4];
  #pragma unroll
  for (int q = 0; q < 8; ++q) {
    float b = bias[c0 + q];
    #pragma unroll
    for (int e = 0; e < 4; ++e) acc[q][e] = b;
  }

  for (int ci = 0; ci < CIN; ++ci) {
    float4 x  = *(const float4*)(inn + o0);
    float xm0 = inn[om]; if (bm) xm0 = 0.f;
    float xp3 = inn[op]; if (bp) xp3 = 0.f;
    o0 += LLEN; om += LLEN; op += LLEN;

    float w[8][3];
    #pragma unroll
    for (int q = 0; q < 8; ++q) {
      const float* wp = W + ((size_t)(c0 + q) * CIN + ci) * 3;
      w[q][0] = wp[0]; w[q][1] = wp[1]; w[q][2] = wp[2];
    }
    #pragma unroll
    for (int q = 0; q < 8; ++q) {
      acc[q][0] = fmaf(xm0, w[q][0], fmaf(x.x, w[q][1], fmaf(x.y, w[q][2], acc[q][0])));
      acc[q][1] = fmaf(x.x, w[q][0], fmaf(x.y, w[q][1], fmaf(x.z, w[q][2], acc[q][1])));
      acc[q][2] = fmaf(x.y, w[q][0], fmaf(x.z, w[q][1], fmaf(x.w, w[q][2], acc[q][2])));
      acc[q][3] = fmaf(x.z, w[q][0], fmaf(x.w, w[q][1], fmaf(xp3, w[q][2], acc[q][3])));
    }
  }

  #pragma unroll
  for (int q = 0; q < 8; ++q) {
    float4 r;
    r.x = lrelu_s(acc[q][0], slope);
    r.y = lrelu_s(acc[q][1], slope);
    r.z = lrelu_s(acc[q][2], slope);
    r.w = lrelu_s(acc[q][3], slope);
    *(float4*)(out + ((size_t)n * COUT + c0 + q) * LLEN + lbase) = r;
  }
}

// conv3 (128->256, lrelu) fused with 3 x Linear(2048->2) heads; h3 never
// materialized. Same lane-vectorized structure; heads accumulated in an
// epilogue, reduced across the wave, atomicAdd into zeroed cm/sm/sl
// (biases applied later in group_reparam). Grid (64, 8, 8).
__global__ __launch_bounds__(256) void conv3_heads_lv(
    const float* __restrict__ h2, const float* __restrict__ W3,
    const float* __restrict__ b3,
    const float* __restrict__ cmW, const float* __restrict__ smW,
    const float* __restrict__ slW,
    float* __restrict__ cm, float* __restrict__ sm, float* __restrict__ sl)
{
  const int n    = blockIdx.x;
  const int wv   = __builtin_amdgcn_readfirstlane(threadIdx.x >> 6);
  const int c0   = blockIdx.y * 32 + wv * 8;
  const int lane = threadIdx.x & 63;
  const int lbase = blockIdx.z * 256 + lane * 4;
  const float* inn = h2 + (size_t)n * 128 * 2048;

  const bool bm = (lbase == 0);
  const bool bp = (lbase + 4 == 2048);
  unsigned o0 = (unsigned)lbase;
  unsigned om = (unsigned)lbase - 1u + (bm ? 1u : 0u);
  unsigned op = (unsigned)lbase + 4u - (bp ? 1u : 0u);

  float acc[8][4];
  #pragma unroll
  for (int q = 0; q < 8; ++q) {
    float b = b3[c0 + q];
    #pragma unroll
    for (int e = 0; e < 4; ++e) acc[q][e] = b;
  }

  for (int ci = 0; ci < 128; ++ci) {
    float4 x  = *(const float4*)(inn + o0);
    float xm0 = inn[om]; if (bm) xm0 = 0.f;
    float xp3 = inn[op]; if (bp) xp3 = 0.f;
    o0 += 2048; om += 2048; op += 2048;

    float w[8][3];
    #pragma unroll
    for (int q = 0; q < 8; ++q) {
      const float* wp = W3 + ((size_t)(c0 + q) * 128 + ci) * 3;
      w[q][0] = wp[0]; w[q][1] = wp[1]; w[q][2] = wp[2];
    }
    #pragma unroll
    for (int q = 0; q < 8; ++q) {
      acc[q][0] = fmaf(xm0, w[q][0], fmaf(x.x, w[q][1], fmaf(x.y, w[q][2], acc[q][0])));
      acc[q][1] = fmaf(x.x, w[q][0], fmaf(x.y, w[q][1], fmaf(x.z, w[q][2], acc[q][1])));
      acc[q][2] = fmaf(x.y, w[q][0], fmaf(x.z, w[q][1], fmaf(x.w, w[q][2], acc[q][2])));
      acc[q][3] = fmaf(x.z, w[q][0], fmaf(x.w, w[q][1], fmaf(xp3, w[q][2], acc[q][3])));
    }
  }

  // epilogue: lrelu + head dot-product partials
  float hw[4][6];
  #pragma unroll
  for (int e = 0; e < 4; ++e) {
    int l = lbase + e;
    hw[e][0] = cmW[l]; hw[e][1] = cmW[2048 + l];
    hw[e][2] = smW[l]; hw[e][3] = smW[2048 + l];
    hw[e][4] = slW[l]; hw[e][5] = slW[2048 + l];
  }
  float hacc[8][6];
  #pragma unroll
  for (int q = 0; q < 8; ++q)
    #pragma unroll
    for (int h = 0; h < 6; ++h) hacc[q][h] = 0.f;

  #pragma unroll
  for (int q = 0; q < 8; ++q)
    #pragma unroll
    for (int e = 0; e < 4; ++e) {
      float v = acc[q][e];
      v = v > 0.f ? v : 0.01f * v;
      #pragma unroll
      for (int h = 0; h < 6; ++h) hacc[q][h] = fmaf(v, hw[e][h], hacc[q][h]);
    }

  #pragma unroll
  for (int q = 0; q < 8; ++q)
    #pragma unroll
    for (int h = 0; h < 6; ++h) {
      float v = hacc[q][h];
      for (int off = 32; off > 0; off >>= 1) v += __shfl_down(v, off, 64);
      hacc[q][h] = v;
    }

  if (lane == 0) {
    #pragma unroll
    for (int q = 0; q < 8; ++q) {
      const int c = c0 + q;
      atomicAdd(&cm[(size_t)n * 512 + c * 2 + 0], hacc[q][0]);
      atomicAdd(&cm[(size_t)n * 512 + c * 2 + 1], hacc[q][1]);
      atomicAdd(&sm[(size_t)n * 512 + c * 2 + 0], hacc[q][2]);
      atomicAdd(&sm[(size_t)n * 512 + c * 2 + 1], hacc[q][3]);
      atomicAdd(&sl[(size_t)n * 512 + c * 2 + 0], hacc[q][4]);
      atomicAdd(&sl[(size_t)n * 512 + c * 2 + 1], hacc[q][5]);
    }
  }
}

// Small-L (LLEN=64) conv: lane = l, wave = 8 channels, taps via shuffles.
template<int CIN, int COUT>
__global__ __launch_bounds__(256) void convs64(
    const float* __restrict__ in, const float* __restrict__ W,
    const float* __restrict__ bias, float* __restrict__ out, float slope)
{
  const int n    = blockIdx.x;
  const int wv   = __builtin_amdgcn_readfirstlane(threadIdx.x >> 6);
  const int c0   = blockIdx.y * 32 + wv * 8;
  const int lane = threadIdx.x & 63;
  const float* inn = in + (size_t)n * CIN * 64;

  float acc[8];
  #pragma unroll
  for (int q = 0; q < 8; ++q) acc[q] = bias[c0 + q];

  unsigned o = (unsigned)lane;
  for (int ci = 0; ci < CIN; ++ci) {
    float x0 = inn[o];
    o += 64;
    float xm = __shfl_up(x0, 1);   if (lane == 0)  xm = 0.f;
    float xp = __shfl_down(x0, 1); if (lane == 63) xp = 0.f;
    float w[8][3];
    #pragma unroll
    for (int q = 0; q < 8; ++q) {
      const float* wp = W + ((size_t)(c0 + q) * CIN + ci) * 3;
      w[q][0] = wp[0]; w[q][1] = wp[1]; w[q][2] = wp[2];
    }
    #pragma unroll
    for (int q = 0; q < 8; ++q)
      acc[q] = fmaf(xm, w[q][0], fmaf(x0, w[q][1], fmaf(xp, w[q][2], acc[q])));
  }
  #pragma unroll
  for (int q = 0; q < 8; ++q)
    out[((size_t)n * COUT + c0 + q) * 64 + lane] = lrelu_s(acc[q], slope);
}

__global__ void zero_kernel(float* __restrict__ p, int nfloat) {
  int i = blockIdx.x * 256 + threadIdx.x;
  if (i < nfloat) p[i] = 0.f;
}

// group-evidence fusion + reparameterization (biases folded in here, since
// conv3_heads accumulates raw sums via atomics)
__global__ __launch_bounds__(256) void group_reparam_kernel(
    const float* __restrict__ cm, const float* __restrict__ sm,
    const float* __restrict__ sl,
    const float* __restrict__ cmB, const float* __restrict__ smB,
    const float* __restrict__ slB,
    const float* __restrict__ eps_c, const float* __restrict__ eps_s,
    float* __restrict__ zc, float* __restrict__ zs)
{
  const int j = blockIdx.x * 256 + threadIdx.x;
  if (j >= 512) return;
  const int d = j & 1;
  const float cb = cmB[d], sb = smB[d], lb = slB[d];
  float sp = 0.f, smp = 0.f;
  for (int n = 0; n < 64; ++n) {
    float mu = cm[n * 512 + j] + cb;
    float p  = expf(-mu);          // class_logvar == class_mu (bug-faithful)
    sp += p;
    smp = fmaf(mu, p, smp);
  }
  float gv  = 1.f / sp;
  float gmu = gv * smp;
  zc[j] = eps_c[j] * sqrtf(gv) + gmu;
  for (int n = 0; n < 64; ++n)
    zs[n * 512 + j] = eps_s[n * 512 + j] * expf(0.5f * (sl[n * 512 + j] + lb))
                      + (sm[n * 512 + j] + sb);
}

// content = pc_W[16384,512] @ z_c + pc_b ; one wave per row
__global__ __launch_bounds__(256) void matvec_content_kernel(
    const float* __restrict__ pcW, const float* __restrict__ pcb,
    const float* __restrict__ zc, float* __restrict__ content)
{
  const int r    = blockIdx.x * 4 + (threadIdx.x >> 6);
  const int lane = threadIdx.x & 63;
  const float* row = pcW + (size_t)r * 512;
  float s = 0.f;
  #pragma unroll
  for (int i = 0; i < 8; ++i) {
    int k = lane + i * 64;
    s = fmaf(row[k], zc[k], s);
  }
  for (int off = 32; off > 0; off >>= 1) s += __shfl_down(s, off, 64);
  if (lane == 0) content[r] = s + pcb[r];
}

// m0[n,r] = zs[n,:] . psW[r,:] + psb[r]. Block: 16 rows in LDS (broadcast
// reads), 4 waves = 4 row-groups, lane = n, 4 rows per thread.
__global__ __launch_bounds__(256) void gemm_m0_kernel(
    const float* __restrict__ psW, const float* __restrict__ psb,
    const float* __restrict__ zs, float* __restrict__ m0)
{
  __shared__ float wrow[16][512];
  const int r0 = blockIdx.x * 16;
  for (int idx = threadIdx.x; idx < 2048; idx += 256)
    ((float4*)wrow)[idx] = ((const float4*)(psW + (size_t)r0 * 512))[idx];
  __syncthreads();
  const int rs = threadIdx.x >> 6;   // wave id -> row group (uniform)
  const int nn = threadIdx.x & 63;
  const float* zr = zs + nn * 512;
  float a0 = 0.f, a1 = 0.f, a2 = 0.f, a3 = 0.f;
  for (int k = 0; k < 512; k += 4) {
    float4 z  = *(const float4*)(zr + k);
    float4 w0 = *(const float4*)(&wrow[rs * 4 + 0][k]);
    float4 w1 = *(const float4*)(&wrow[rs * 4 + 1][k]);
    float4 w2 = *(const float4*)(&wrow[rs * 4 + 2][k]);
    float4 w3 = *(const float4*)(&wrow[rs * 4 + 3][k]);
    a0 = fmaf(z.x, w0.x, fmaf(z.y, w0.y, fmaf(z.z, w0.z, fmaf(z.w, w0.w, a0))));
    a1 = fmaf(z.x, w1.x, fmaf(z.y, w1.y, fmaf(z.z, w1.z, fmaf(z.w, w1.w, a1))));
    a2 = fmaf(z.x, w2.x, fmaf(z.y, w2.y, fmaf(z.z, w2.z, fmaf(z.w, w2.w, a2))));
    a3 = fmaf(z.x, w3.x, fmaf(z.y, w3.y, fmaf(z.z, w3.z, fmaf(z.w, w3.w, a3))));
  }
  const int rb = r0 + rs * 4;
  m0[(size_t)nn * 16384 + rb + 0] = a0 + psb[rb + 0];
  m0[(size_t)nn * 16384 + rb + 1] = a1 + psb[rb + 1];
  m0[(size_t)nn * 16384 + rb + 2] = a2 + psb[rb + 2];
  m0[(size_t)nn * 16384 + rb + 3] = a3 + psb[rb + 3];
}

// Full 1-D convolution partials: out[n,k] = sum_j m2[n,j]*src[k-j].
// j-range split 4 ways (blockIdx.z); per-thread 8-k sliding register window.
__global__ __launch_bounds__(256) void final_conv_part_kernel(
    const float* __restrict__ m2, const float* __restrict__ src,
    float* __restrict__ part)
{
  __shared__ float s_src[4096];
  __shared__ float s_m[1024];
  const int n  = blockIdx.x;
  const int J0 = blockIdx.z * 1024;
  for (int i = threadIdx.x; i < 4096; i += 256) s_src[i] = src[i];
  for (int i = threadIdx.x; i < 1024; i += 256) s_m[i] = m2[(size_t)n * 4096 + J0 + i];
  __syncthreads();

  const int k0 = blockIdx.y * 2048 + threadIdx.x * 8;
  int jlo = k0 - 4095; if (jlo < J0) jlo = J0;
  int jhi = k0 + 7;    if (jhi > J0 + 1023) jhi = J0 + 1023;

  float acc[8];
  #pragma unroll
  for (int ii = 0; ii < 8; ++ii) acc[ii] = 0.f;

  float Wr[8];
  #pragma unroll
  for (int p = 0; p < 8; ++p) {
    int d  = k0 + p - jlo;
    int dc = d & 4095;
    float v = s_src[dc];
    Wr[p] = (d == dc) ? v : 0.f;
  }

  int j = jlo;
  for (; j + 7 <= jhi; j += 8) {
    #pragma unroll
    for (int s = 0; s < 8; ++s) {
      float mj = s_m[j + s - J0];
      #pragma unroll
      for (int ii = 0; ii < 8; ++ii)
        acc[ii] = fmaf(mj, Wr[(ii - s) & 7], acc[ii]);
      int d  = k0 - (j + s) - 1;
      int dc = d < 0 ? 0 : d;
      float nv = s_src[dc];
      if (d < 0) nv = 0.f;
      Wr[(7 - s) & 7] = nv;
    }
  }
  for (; j <= jhi; ++j) {
    float mj = s_m[j - J0];
    #pragma unroll
    for (int ii = 0; ii < 8; ++ii) {
      int d  = k0 + ii - j;
      int dc = d & 4095;
      float sv = s_src[dc];
      if (d != dc) sv = 0.f;
      acc[ii] = fmaf(mj, sv, acc[ii]);
    }
  }

  float* po = part + ((size_t)(blockIdx.z * 64 + n)) * 8192 + k0;
  #pragma unroll
  for (int ii = 0; ii < 8; ++ii) po[ii] = acc[ii];
}

__global__ void combine_kernel(const float* __restrict__ part,
                               float* __restrict__ out) {
  int i = blockIdx.x * 256 + threadIdx.x;
  if (i >= 64 * 8191) return;
  int n = i / 8191, k = i - n * 8191;
  float s = 0.f;
  #pragma unroll
  for (int js = 0; js < 4; ++js)
    s += part[((size_t)(js * 64 + n)) * 8192 + k];
  out[i] = s;
}

extern "C" void kernel_launch(void* const* d_in, const int* in_sizes, int n_in,
                              void* d_out, int out_size, void* d_ws, size_t ws_size,
                              hipStream_t stream) {
  const float* x    = (const float*)d_in[0];
  const float* W1   = (const float*)d_in[1];
  const float* b1   = (const float*)d_in[2];
  const float* W2   = (const float*)d_in[3];
  const float* b2   = (const float*)d_in[4];
  const float* W3   = (const float*)d_in[5];
  const float* b3   = (const float*)d_in[6];
  const float* cmW  = (const float*)d_in[7];
  const float* cmB  = (const float*)d_in[8];
  const float* smW  = (const float*)d_in[9];
  const float* smB  = (const float*)d_in[10];
  const float* slW  = (const float*)d_in[11];
  const float* slB  = (const float*)d_in[12];
  const float* pcW  = (const float*)d_in[13];
  const float* pcb  = (const float*)d_in[14];
  const float* psW  = (const float*)d_in[15];
  const float* psb  = (const float*)d_in[16];
  const float* V1   = (const float*)d_in[17];
  const float* c1   = (const float*)d_in[18];
  const float* V2   = (const float*)d_in[19];
  const float* c2   = (const float*)d_in[20];
  const float* epsc = (const float*)d_in[21];
  const float* epss = (const float*)d_in[22];
  float* out = (float*)d_out;

  // Workspace layout (floats). h1/h2 live first; small buffers overlay h1
  // (dead after conv2 consumed it).
  float* ws = (float*)d_ws;
  float* h1 = ws;                    // [64][64][2048]   = 8388608 f
  float* h2 = h1 + 8388608;          // [64][128][2048]  = 16777216 f
  float* cm      = h1;               // [64][512] (raw head sums, overlay)
  float* smh     = cm + 32768;       // [64][512]
  float* slh     = smh + 32768;      // [64][512]
  float* zc      = slh + 32768;      // [512]
  float* zs      = zc + 512;         // [64][512]
  float* content = zs + 32768;       // [16384]
  float* d1s     = content + 16384;  // [128][64]
  float* srcb    = d1s + 8192;       // [4096]
  float* m0      = srcb + 4096;      // [64][16384] = 1048576 f
  float* m1      = m0 + 1048576;     // [64][128][64] = 524288 f
  float* m2      = m1 + 524288;      // [64][64][64]  = 262144 f
  float* part    = m2 + 262144;      // [4][64][8192] = 2097152 f
  (void)ws_size; (void)in_sizes; (void)n_in; (void)out_size;

  // ---- encoder ----
  convlv<1,   64, 2048><<<dim3(64, 2, 8), 256, 0, stream>>>(x,  W1, b1, h1, 0.01f);
  convlv<64, 128, 2048><<<dim3(64, 4, 8), 256, 0, stream>>>(h1, W2, b2, h2, 0.01f);
  zero_kernel<<<384, 256, 0, stream>>>(cm, 98304);   // cm+smh+slh (after conv2!)
  conv3_heads_lv<<<dim3(64, 8, 8), 256, 0, stream>>>(h2, W3, b3, cmW, smW, slW,
                                                     cm, smh, slh);
  // ---- group evidence + reparameterize ----
  group_reparam_kernel<<<2, 256, 0, stream>>>(cm, smh, slh, cmB, smB, slB,
                                              epsc, epss, zc, zs);

  // ---- content path: projection + 2 convs -> source ----
  matvec_content_kernel<<<4096, 256, 0, stream>>>(pcW, pcb, zc, content);
  convs64<256, 128><<<dim3(1, 4), 256, 0, stream>>>(content, V1, c1, d1s, 0.f);
  convs64<128,  64><<<dim3(1, 2), 256, 0, stream>>>(d1s,     V2, c2, srcb, 0.f);

  // ---- style path: GEMM + 2 convs ----
  gemm_m0_kernel<<<1024, 256, 0, stream>>>(psW, psb, zs, m0);
  convs64<256, 128><<<dim3(64, 4), 256, 0, stream>>>(m0, V1, c1, m1, 0.f);
  convs64<128,  64><<<dim3(64, 2), 256, 0, stream>>>(m1, V2, c2, m2, 0.f);

  // ---- final full 1-D convolution (j-split partials + combine) ----
  final_conv_part_kernel<<<dim3(64, 4, 4), 256, 0, stream>>>(m2, srcb, part);
  combine_kernel<<<2048, 256, 0, stream>>>(part, out);
}

// Round 5
// 621.154 us; speedup vs baseline: 3.7307x; 1.7841x over previous
//
#include <hip/hip_runtime.h>
#include <math.h>

// ---------------------------------------------------------------------------
// MLVAE pipeline. Encoder conv2/conv3 on MFMA (bf16x3 split = f32-accuracy),
// rest f32 VALU. Dims: N=64, L=2048, C1=64, C2=128, C3=256, LAT=512, LD=64.
// ---------------------------------------------------------------------------

using short8  = __attribute__((ext_vector_type(8))) short;
using floatx4 = __attribute__((ext_vector_type(4))) float;

__device__ __forceinline__ float lrelu_s(float v, float slope) {
  return v > 0.f ? v : slope * v;
}
__device__ __forceinline__ unsigned short bf16_rne(float f) {
  unsigned u = __float_as_uint(f);
  u += 0x7FFFu + ((u >> 16) & 1u);
  return (unsigned short)(u >> 16);
}
__device__ __forceinline__ float bf16_to_f(unsigned short h) {
  return __uint_as_float(((unsigned)h) << 16);
}

// Split conv weights W[co][ci][3] f32 -> [t][co][ci] bf16 hi/lo planes.
__global__ __launch_bounds__(256) void prep_weights_kernel(
    const float* __restrict__ W2, const float* __restrict__ W3,
    unsigned short* __restrict__ w2hi, unsigned short* __restrict__ w2lo,
    unsigned short* __restrict__ w3hi, unsigned short* __restrict__ w3lo)
{
  int id = blockIdx.x * 256 + threadIdx.x;
  if (id < 24576) {                      // W2: [128][64][3]
    int t = id % 3, rem = id / 3;
    int ci = rem % 64, co = rem / 64;
    float w = W2[id];
    unsigned short hi = bf16_rne(w);
    unsigned short lo = bf16_rne(w - bf16_to_f(hi));
    int o = (t * 128 + co) * 64 + ci;
    w2hi[o] = hi; w2lo[o] = lo;
  } else if (id < 24576 + 98304) {       // W3: [256][128][3]
    int i3 = id - 24576;
    int t = i3 % 3, rem = i3 / 3;
    int ci = rem % 128, co = rem / 128;
    float w = W3[i3];
    unsigned short hi = bf16_rne(w);
    unsigned short lo = bf16_rne(w - bf16_to_f(hi));
    int o = (t * 256 + co) * 128 + ci;
    w3hi[o] = hi; w3lo[o] = lo;
  }
}

// conv1 (CIN=1): lane-vectorized f32 (tiny FLOPs, keep on VALU).
template<int CIN, int COUT, int LLEN>
__global__ __launch_bounds__(256) void convlv(
    const float* __restrict__ in, const float* __restrict__ W,
    const float* __restrict__ bias, float* __restrict__ out, float slope)
{
  const int n    = blockIdx.x;
  const int wv   = __builtin_amdgcn_readfirstlane(threadIdx.x >> 6);
  const int c0   = blockIdx.y * 32 + wv * 8;
  const int lane = threadIdx.x & 63;
  const int lbase = blockIdx.z * 256 + lane * 4;
  const float* inn = in + (size_t)n * CIN * LLEN;

  const bool bm = (lbase == 0);
  const bool bp = (lbase + 4 == LLEN);
  unsigned o0 = (unsigned)lbase;
  unsigned om = (unsigned)lbase - 1u + (bm ? 1u : 0u);
  unsigned op = (unsigned)lbase + 4u - (bp ? 1u : 0u);

  float acc[8][4];
  #pragma unroll
  for (int q = 0; q < 8; ++q) {
    float b = bias[c0 + q];
    #pragma unroll
    for (int e = 0; e < 4; ++e) acc[q][e] = b;
  }
  for (int ci = 0; ci < CIN; ++ci) {
    float4 x  = *(const float4*)(inn + o0);
    float xm0 = inn[om]; if (bm) xm0 = 0.f;
    float xp3 = inn[op]; if (bp) xp3 = 0.f;
    o0 += LLEN; om += LLEN; op += LLEN;
    float w[8][3];
    #pragma unroll
    for (int q = 0; q < 8; ++q) {
      const float* wp = W + ((size_t)(c0 + q) * CIN + ci) * 3;
      w[q][0] = wp[0]; w[q][1] = wp[1]; w[q][2] = wp[2];
    }
    #pragma unroll
    for (int q = 0; q < 8; ++q) {
      acc[q][0] = fmaf(xm0, w[q][0], fmaf(x.x, w[q][1], fmaf(x.y, w[q][2], acc[q][0])));
      acc[q][1] = fmaf(x.x, w[q][0], fmaf(x.y, w[q][1], fmaf(x.z, w[q][2], acc[q][1])));
      acc[q][2] = fmaf(x.y, w[q][0], fmaf(x.z, w[q][1], fmaf(x.w, w[q][2], acc[q][2])));
      acc[q][3] = fmaf(x.z, w[q][0], fmaf(x.w, w[q][1], fmaf(xp3, w[q][2], acc[q][3])));
    }
  }
  #pragma unroll
  for (int q = 0; q < 8; ++q) {
    float4 r;
    r.x = lrelu_s(acc[q][0], slope);
    r.y = lrelu_s(acc[q][1], slope);
    r.z = lrelu_s(acc[q][2], slope);
    r.w = lrelu_s(acc[q][3], slope);
    *(float4*)(out + ((size_t)n * COUT + c0 + q) * LLEN + lbase) = r;
  }
}

// MFMA implicit-GEMM conv1d k=3 'same' + lrelu(0.01), bf16x3 split.
// Grid (n, COUT/128, 2048/128). Block 256 = 4 waves (2m x 2n), wave tile
// 64co x 64l = 4x4 frags of 16x16x32. K-loop: ci steps of 32, 3 t-shift
// passes per step reading a shared transposed B tile.
// HEADS: fuse lrelu + 3x Linear(2048->2) partials -> hpart[lt][n][3][512].
template<int CIN, int COUT, bool HEADS>
__global__ __launch_bounds__(256, 3) void conv_mfma(
    const float* __restrict__ in, const unsigned short* __restrict__ Whi,
    const unsigned short* __restrict__ Wlo, const float* __restrict__ bias,
    float* __restrict__ out, float* __restrict__ hpart,
    const float* __restrict__ cmW, const float* __restrict__ smW,
    const float* __restrict__ slW)
{
  // LDS map (ushort units): Bhi[130][40] @0, Blo @5200, Ahi[128][40] @10400,
  // Alo @15520, hw f32[6][128] @20640. Epilogue H f32[64][132] overlays @0.
  __shared__ unsigned short smem[22176];
  const int tid  = threadIdx.x;
  const int n    = blockIdx.x;
  const int coT  = blockIdx.y;
  const int lt   = blockIdx.z;
  const int l0   = lt * 128;
  const int wid  = __builtin_amdgcn_readfirstlane(tid >> 6);
  const int wm   = wid >> 1, wn = wid & 1;
  const int lane = tid & 63;
  const int l16  = lane & 15, lk = lane >> 4;
  const float* inn = in + (size_t)n * CIN * 2048;

  if (HEADS) {   // stage head weights for this l-tile
    for (int idx = tid; idx < 768; idx += 256) {
      int h6 = idx >> 7, l = idx & 127;
      const float* src = (h6 < 2) ? cmW : (h6 < 4 ? smW : slW);
      ((float*)(smem + 20640))[idx] = src[(h6 & 1) * 2048 + l0 + l];
    }
  }

  floatx4 acc[4][4];
  #pragma unroll
  for (int mf = 0; mf < 4; ++mf) {
    #pragma unroll
    for (int r = 0; r < 4; ++r) {
      float bv = bias[coT * 128 + wm * 64 + mf * 16 + lk * 4 + r];
      #pragma unroll
      for (int nf = 0; nf < 4; ++nf) acc[mf][nf][r] = bv;
    }
  }

  const int s_steps = CIN / 32;
  for (int s = 0; s < s_steps; ++s) {
    const int ci0 = s * 32;
    __syncthreads();
    // ---- stage B: in[n][ci0..+31][l0-1..l0+128] -> transposed hi/lo ----
    {
      const int l4 = tid >> 3;       // 0..31 (l block of 4)
      const int cb = tid & 7;
      #pragma unroll
      for (int p = 0; p < 4; ++p) {
        int c = cb + 8 * p;
        const float4 v4 = *(const float4*)(inn + (size_t)(ci0 + c) * 2048 + l0 + l4 * 4);
        #pragma unroll
        for (int e = 0; e < 4; ++e) {
          float v = (&v4.x)[e];
          unsigned short hi = bf16_rne(v);
          unsigned short lo = bf16_rne(v - bf16_to_f(hi));
          int r = l4 * 4 + e + 1;
          smem[r * 40 + c]        = hi;
          smem[5200 + r * 40 + c] = lo;
        }
      }
      if (tid < 64) {                // edge columns r=0 (l0-1), r=129 (l0+128)
        int ce = tid & 31, e = tid >> 5;
        int le = e ? (l0 + 128) : (l0 - 1);
        float v = 0.f;
        if (le >= 0 && le < 2048) v = inn[(size_t)(ci0 + ce) * 2048 + le];
        unsigned short hi = bf16_rne(v);
        unsigned short lo = bf16_rne(v - bf16_to_f(hi));
        int r = e ? 129 : 0;
        smem[r * 40 + ce]        = hi;
        smem[5200 + r * 40 + ce] = lo;
      }
    }
    #pragma unroll
    for (int t = 0; t < 3; ++t) {
      if (t > 0) __syncthreads();
      // ---- stage A_t: pre-split weights [t][co][ci] ----
      {
        int co  = tid >> 1;
        int h16 = (tid & 1) * 16;
        const size_t gb = ((size_t)(t * COUT) + coT * 128 + co) * CIN + ci0 + h16;
        #pragma unroll
        for (int p = 0; p < 2; ++p) {
          short8 hi = *(const short8*)(Whi + gb + 8 * p);
          short8 lo = *(const short8*)(Wlo + gb + 8 * p);
          *(short8*)(smem + 10400 + co * 40 + h16 + 8 * p) = hi;
          *(short8*)(smem + 15520 + co * 40 + h16 + 8 * p) = lo;
        }
      }
      __syncthreads();
      // ---- compute: 4x4 frags, 3-pass split MFMA ----
      short8 ahi[4], alo[4];
      #pragma unroll
      for (int mf = 0; mf < 4; ++mf) {
        int off = (wm * 64 + mf * 16 + l16) * 40 + lk * 8;
        ahi[mf] = *(const short8*)(smem + 10400 + off);
        alo[mf] = *(const short8*)(smem + 15520 + off);
      }
      #pragma unroll
      for (int nf = 0; nf < 4; ++nf) {
        int rr  = wn * 64 + nf * 16 + l16 + t;
        int off = rr * 40 + lk * 8;
        short8 bhi = *(const short8*)(smem + off);
        short8 blo = *(const short8*)(smem + 5200 + off);
        #pragma unroll
        for (int mf = 0; mf < 4; ++mf) {
          acc[mf][nf] = __builtin_amdgcn_mfma_f32_16x16x32_bf16(ahi[mf], bhi, acc[mf][nf], 0, 0, 0);
          acc[mf][nf] = __builtin_amdgcn_mfma_f32_16x16x32_bf16(ahi[mf], blo, acc[mf][nf], 0, 0, 0);
          acc[mf][nf] = __builtin_amdgcn_mfma_f32_16x16x32_bf16(alo[mf], bhi, acc[mf][nf], 0, 0, 0);
        }
      }
    }
  }

  if (!HEADS) {
    // lrelu + store h2 f32
    #pragma unroll
    for (int mf = 0; mf < 4; ++mf)
      #pragma unroll
      for (int nf = 0; nf < 4; ++nf)
        #pragma unroll
        for (int r = 0; r < 4; ++r) {
          float v = lrelu_s(acc[mf][nf][r], 0.01f);
          out[((size_t)n * COUT + coT * 128 + wm * 64 + mf * 16 + lk * 4 + r) * 2048
              + l0 + wn * 64 + nf * 16 + l16] = v;
        }
  } else {
    float* H = (float*)smem;
    const float* hwl = (const float*)(smem + 20640);
    #pragma unroll
    for (int p = 0; p < 2; ++p) {
      __syncthreads();
      if (wm == p) {
        #pragma unroll
        for (int mf = 0; mf < 4; ++mf)
          #pragma unroll
          for (int nf = 0; nf < 4; ++nf)
            #pragma unroll
            for (int r = 0; r < 4; ++r) {
              float v = lrelu_s(acc[mf][nf][r], 0.01f);
              H[(mf * 16 + lk * 4 + r) * 132 + wn * 64 + nf * 16 + l16] = v;
            }
      }
      __syncthreads();
      int co = tid >> 2, q = tid & 3;
      float sacc[6] = {0.f, 0.f, 0.f, 0.f, 0.f, 0.f};
      #pragma unroll
      for (int e4 = 0; e4 < 8; ++e4) {
        float4 hv = *(const float4*)(H + co * 132 + q * 32 + e4 * 4);
        #pragma unroll
        for (int ee = 0; ee < 4; ++ee) {
          float v = (&hv.x)[ee];
          int ll = q * 32 + e4 * 4 + ee;
          #pragma unroll
          for (int h6 = 0; h6 < 6; ++h6)
            sacc[h6] = fmaf(v, hwl[h6 * 128 + ll], sacc[h6]);
        }
      }
      #pragma unroll
      for (int h6 = 0; h6 < 6; ++h6) {
        sacc[h6] += __shfl_xor(sacc[h6], 1);
        sacc[h6] += __shfl_xor(sacc[h6], 2);
      }
      if (q == 0) {
        int j = (coT * 128 + p * 64 + co) * 2;
        #pragma unroll
        for (int hd = 0; hd < 3; ++hd) {
          float2 st = make_float2(sacc[hd * 2], sacc[hd * 2 + 1]);
          *(float2*)(hpart + ((size_t)((lt * 64 + n) * 3 + hd)) * 512 + j) = st;
        }
      }
    }
  }
}

// Sum 16 l-tile head partials -> cm/sm/sl raw sums [64][512].
__global__ __launch_bounds__(256) void head_combine_kernel(
    const float* __restrict__ hpart, float* __restrict__ cm,
    float* __restrict__ smv, float* __restrict__ sl)
{
  int n = blockIdx.x;
  int j = threadIdx.x * 2;
  float2 s0 = {0.f, 0.f}, s1 = {0.f, 0.f}, s2 = {0.f, 0.f};
  for (int ltt = 0; ltt < 16; ++ltt) {
    const float* base = hpart + ((size_t)((ltt * 64 + n) * 3)) * 512 + j;
    float2 a = *(const float2*)(base);
    float2 b = *(const float2*)(base + 512);
    float2 c = *(const float2*)(base + 1024);
    s0.x += a.x; s0.y += a.y;
    s1.x += b.x; s1.y += b.y;
    s2.x += c.x; s2.y += c.y;
  }
  *(float2*)(cm  + n * 512 + j) = s0;
  *(float2*)(smv + n * 512 + j) = s1;
  *(float2*)(sl  + n * 512 + j) = s2;
}

// group-evidence fusion + reparameterization (biases folded here)
__global__ __launch_bounds__(256) void group_reparam_kernel(
    const float* __restrict__ cm, const float* __restrict__ sm,
    const float* __restrict__ sl,
    const float* __restrict__ cmB, const float* __restrict__ smB,
    const float* __restrict__ slB,
    const float* __restrict__ eps_c, const float* __restrict__ eps_s,
    float* __restrict__ zc, float* __restrict__ zs)
{
  const int j = blockIdx.x * 256 + threadIdx.x;
  if (j >= 512) return;
  const int d = j & 1;
  const float cb = cmB[d], sb = smB[d], lb = slB[d];
  float sp = 0.f, smp = 0.f;
  for (int n = 0; n < 64; ++n) {
    float mu = cm[n * 512 + j] + cb;
    float p  = expf(-mu);          // class_logvar == class_mu (bug-faithful)
    sp += p;
    smp = fmaf(mu, p, smp);
  }
  float gv  = 1.f / sp;
  float gmu = gv * smp;
  zc[j] = eps_c[j] * sqrtf(gv) + gmu;
  for (int n = 0; n < 64; ++n)
    zs[n * 512 + j] = eps_s[n * 512 + j] * expf(0.5f * (sl[n * 512 + j] + lb))
                      + (sm[n * 512 + j] + sb);
}

// content = pc_W[16384,512] @ z_c + pc_b ; one wave per row
__global__ __launch_bounds__(256) void matvec_content_kernel(
    const float* __restrict__ pcW, const float* __restrict__ pcb,
    const float* __restrict__ zc, float* __restrict__ content)
{
  const int r    = blockIdx.x * 4 + (threadIdx.x >> 6);
  const int lane = threadIdx.x & 63;
  const float* row = pcW + (size_t)r * 512;
  float s = 0.f;
  #pragma unroll
  for (int i = 0; i < 8; ++i) {
    int k = lane + i * 64;
    s = fmaf(row[k], zc[k], s);
  }
  for (int off = 32; off > 0; off >>= 1) s += __shfl_down(s, off, 64);
  if (lane == 0) content[r] = s + pcb[r];
}

// m0[n,r] = zs[n,:] . psW[r,:] + psb[r]
__global__ __launch_bounds__(256) void gemm_m0_kernel(
    const float* __restrict__ psW, const float* __restrict__ psb,
    const float* __restrict__ zs, float* __restrict__ m0)
{
  __shared__ float wrow[16][512];
  const int r0 = blockIdx.x * 16;
  for (int idx = threadIdx.x; idx < 2048; idx += 256)
    ((float4*)wrow)[idx] = ((const float4*)(psW + (size_t)r0 * 512))[idx];
  __syncthreads();
  const int rs = threadIdx.x >> 6;
  const int nn = threadIdx.x & 63;
  const float* zr = zs + nn * 512;
  float a0 = 0.f, a1 = 0.f, a2 = 0.f, a3 = 0.f;
  for (int k = 0; k < 512; k += 4) {
    float4 z  = *(const float4*)(zr + k);
    float4 w0 = *(const float4*)(&wrow[rs * 4 + 0][k]);
    float4 w1 = *(const float4*)(&wrow[rs * 4 + 1][k]);
    float4 w2 = *(const float4*)(&wrow[rs * 4 + 2][k]);
    float4 w3 = *(const float4*)(&wrow[rs * 4 + 3][k]);
    a0 = fmaf(z.x, w0.x, fmaf(z.y, w0.y, fmaf(z.z, w0.z, fmaf(z.w, w0.w, a0))));
    a1 = fmaf(z.x, w1.x, fmaf(z.y, w1.y, fmaf(z.z, w1.z, fmaf(z.w, w1.w, a1))));
    a2 = fmaf(z.x, w2.x, fmaf(z.y, w2.y, fmaf(z.z, w2.z, fmaf(z.w, w2.w, a2))));
    a3 = fmaf(z.x, w3.x, fmaf(z.y, w3.y, fmaf(z.z, w3.z, fmaf(z.w, w3.w, a3))));
  }
  const int rb = r0 + rs * 4;
  m0[(size_t)nn * 16384 + rb + 0] = a0 + psb[rb + 0];
  m0[(size_t)nn * 16384 + rb + 1] = a1 + psb[rb + 1];
  m0[(size_t)nn * 16384 + rb + 2] = a2 + psb[rb + 2];
  m0[(size_t)nn * 16384 + rb + 3] = a3 + psb[rb + 3];
}

// Decoder small conv (LLEN=64), relu; 65 samples (64 style + 1 content).
template<int CIN, int COUT>
__global__ __launch_bounds__(256) void convs64(
    const float* __restrict__ in0, const float* __restrict__ inC,
    const float* __restrict__ W, const float* __restrict__ bias,
    float* __restrict__ out0, float* __restrict__ outC)
{
  const int n    = blockIdx.x;
  const int wv   = __builtin_amdgcn_readfirstlane(threadIdx.x >> 6);
  const int c0   = blockIdx.y * 32 + wv * 8;
  const int lane = threadIdx.x & 63;
  const float* inn = (n < 64) ? (in0 + (size_t)n * CIN * 64) : inC;
  float* outp      = (n < 64) ? (out0 + (size_t)n * COUT * 64) : outC;

  float acc[8];
  #pragma unroll
  for (int q = 0; q < 8; ++q) acc[q] = bias[c0 + q];

  unsigned o = (unsigned)lane;
  for (int ci = 0; ci < CIN; ++ci) {
    float x0 = inn[o];
    o += 64;
    float xm = __shfl_up(x0, 1);   if (lane == 0)  xm = 0.f;
    float xp = __shfl_down(x0, 1); if (lane == 63) xp = 0.f;
    float w[8][3];
    #pragma unroll
    for (int q = 0; q < 8; ++q) {
      const float* wp = W + ((size_t)(c0 + q) * CIN + ci) * 3;
      w[q][0] = wp[0]; w[q][1] = wp[1]; w[q][2] = wp[2];
    }
    #pragma unroll
    for (int q = 0; q < 8; ++q)
      acc[q] = fmaf(xm, w[q][0], fmaf(x0, w[q][1], fmaf(xp, w[q][2], acc[q])));
  }
  #pragma unroll
  for (int q = 0; q < 8; ++q)
    outp[(size_t)(c0 + q) * 64 + lane] = acc[q] > 0.f ? acc[q] : 0.f;
}

// Full 1-D convolution partials: out[n,k] = sum_j m2[n,j]*src[k-j].
__global__ __launch_bounds__(256) void final_conv_part_kernel(
    const float* __restrict__ m2, const float* __restrict__ src,
    float* __restrict__ part)
{
  __shared__ float s_src[4096];
  __shared__ float s_m[1024];
  const int n  = blockIdx.x;
  const int J0 = blockIdx.z * 1024;
  for (int i = threadIdx.x; i < 4096; i += 256) s_src[i] = src[i];
  for (int i = threadIdx.x; i < 1024; i += 256) s_m[i] = m2[(size_t)n * 4096 + J0 + i];
  __syncthreads();

  const int k0 = blockIdx.y * 2048 + threadIdx.x * 8;
  int jlo = k0 - 4095; if (jlo < J0) jlo = J0;
  int jhi = k0 + 7;    if (jhi > J0 + 1023) jhi = J0 + 1023;

  float acc[8];
  #pragma unroll
  for (int ii = 0; ii < 8; ++ii) acc[ii] = 0.f;

  float Wr[8];
  #pragma unroll
  for (int p = 0; p < 8; ++p) {
    int d  = k0 + p - jlo;
    int dc = d & 4095;
    float v = s_src[dc];
    Wr[p] = (d == dc) ? v : 0.f;
  }
  int j = jlo;
  for (; j + 7 <= jhi; j += 8) {
    #pragma unroll
    for (int s = 0; s < 8; ++s) {
      float mj = s_m[j + s - J0];
      #pragma unroll
      for (int ii = 0; ii < 8; ++ii)
        acc[ii] = fmaf(mj, Wr[(ii - s) & 7], acc[ii]);
      int d  = k0 - (j + s) - 1;
      int dc = d < 0 ? 0 : d;
      float nv = s_src[dc];
      if (d < 0) nv = 0.f;
      Wr[(7 - s) & 7] = nv;
    }
  }
  for (; j <= jhi; ++j) {
    float mj = s_m[j - J0];
    #pragma unroll
    for (int ii = 0; ii < 8; ++ii) {
      int d  = k0 + ii - j;
      int dc = d & 4095;
      float sv = s_src[dc];
      if (d != dc) sv = 0.f;
      acc[ii] = fmaf(mj, sv, acc[ii]);
    }
  }
  float* po = part + ((size_t)(blockIdx.z * 64 + n)) * 8192 + k0;
  #pragma unroll
  for (int ii = 0; ii < 8; ++ii) po[ii] = acc[ii];
}

__global__ void combine_kernel(const float* __restrict__ part,
                               float* __restrict__ out) {
  int i = blockIdx.x * 256 + threadIdx.x;
  if (i >= 64 * 8191) return;
  int n = i / 8191, k = i - n * 8191;
  float s = 0.f;
  #pragma unroll
  for (int js = 0; js < 4; ++js)
    s += part[((size_t)(js * 64 + n)) * 8192 + k];
  out[i] = s;
}

extern "C" void kernel_launch(void* const* d_in, const int* in_sizes, int n_in,
                              void* d_out, int out_size, void* d_ws, size_t ws_size,
                              hipStream_t stream) {
  const float* x    = (const float*)d_in[0];
  const float* W1   = (const float*)d_in[1];
  const float* b1   = (const float*)d_in[2];
  const float* W2   = (const float*)d_in[3];
  const float* b2   = (const float*)d_in[4];
  const float* W3   = (const float*)d_in[5];
  const float* b3   = (const float*)d_in[6];
  const float* cmW  = (const float*)d_in[7];
  const float* cmB  = (const float*)d_in[8];
  const float* smW  = (const float*)d_in[9];
  const float* smB  = (const float*)d_in[10];
  const float* slW  = (const float*)d_in[11];
  const float* slB  = (const float*)d_in[12];
  const float* pcW  = (const float*)d_in[13];
  const float* pcb  = (const float*)d_in[14];
  const float* psW  = (const float*)d_in[15];
  const float* psb  = (const float*)d_in[16];
  const float* V1   = (const float*)d_in[17];
  const float* c1   = (const float*)d_in[18];
  const float* V2   = (const float*)d_in[19];
  const float* c2   = (const float*)d_in[20];
  const float* epsc = (const float*)d_in[21];
  const float* epss = (const float*)d_in[22];
  float* out = (float*)d_out;

  // Workspace (floats). h1/h2 first; everything else overlays h1 after conv2.
  float* ws = (float*)d_ws;
  float* h1 = ws;                     // [64][64][2048]   = 8388608 f
  float* h2 = h1 + 8388608;           // [64][128][2048]  = 16777216 f
  float* hpart   = h1;                // [16][64][3][512] = 1572864 f
  float* cm      = h1 + 1572864;      // [64][512]
  float* smh     = h1 + 1605632;      // [64][512]
  float* slh     = h1 + 1638400;      // [64][512]
  float* zc      = h1 + 1671168;      // [512]
  float* zs      = h1 + 1671680;      // [64][512]
  float* content = h1 + 1704448;      // [16384]
  float* d1s     = h1 + 1720832;      // [128][64]
  float* srcb    = h1 + 1729024;      // [4096]
  float* m0      = h1 + 1733120;      // [64][16384]
  float* m1      = h1 + 2781696;      // [64][128][64]
  float* m2      = h1 + 3305984;      // [64][64][64]
  float* part    = h1 + 3568128;      // [4][64][8192] -> ends 5665280 f
  // Pre-split weight planes live in d_out scratch (combine overwrites last).
  unsigned short* wsp  = (unsigned short*)d_out;
  unsigned short* w2hi = wsp;             // [3][128][64]
  unsigned short* w2lo = wsp + 24576;
  unsigned short* w3hi = wsp + 49152;     // [3][256][128]
  unsigned short* w3lo = wsp + 147456;    // ends 245760 us = 480 KB < out
  (void)ws_size; (void)in_sizes; (void)n_in; (void)out_size;

  prep_weights_kernel<<<480, 256, 0, stream>>>(W2, W3, w2hi, w2lo, w3hi, w3lo);

  // ---- encoder ----
  convlv<1, 64, 2048><<<dim3(64, 2, 8), 256, 0, stream>>>(x, W1, b1, h1, 0.01f);
  conv_mfma<64, 128, false><<<dim3(64, 1, 16), 256, 0, stream>>>(
      h1, w2hi, w2lo, b2, h2, nullptr, cmW, smW, slW);
  conv_mfma<128, 256, true><<<dim3(64, 2, 16), 256, 0, stream>>>(
      h2, w3hi, w3lo, b3, nullptr, hpart, cmW, smW, slW);
  head_combine_kernel<<<64, 256, 0, stream>>>(hpart, cm, smh, slh);

  // ---- group evidence + reparameterize ----
  group_reparam_kernel<<<2, 256, 0, stream>>>(cm, smh, slh, cmB, smB, slB,
                                              epsc, epss, zc, zs);

  // ---- projections ----
  matvec_content_kernel<<<4096, 256, 0, stream>>>(pcW, pcb, zc, content);
  gemm_m0_kernel<<<1024, 256, 0, stream>>>(psW, psb, zs, m0);

  // ---- shared decoder convs: 64 style samples + content as sample 64 ----
  convs64<256, 128><<<dim3(65, 4), 256, 0, stream>>>(m0, content, V1, c1, m1, d1s);
  convs64<128, 64><<<dim3(65, 2), 256, 0, stream>>>(m1, d1s, V2, c2, m2, srcb);

  // ---- final full 1-D convolution ----
  final_conv_part_kernel<<<dim3(64, 4, 4), 256, 0, stream>>>(m2, srcb, part);
  combine_kernel<<<2048, 256, 0, stream>>>(part, out);
}